// Round 1
// baseline (119.496 us; speedup 1.0000x reference)
//
#include <hip/hip_runtime.h>

// ExactAttention: block-diagonal masked softmax(Q K^T / sqrt(d)) @ V
// N=12288, D=128, 32 sorted batch segments. Global-max / EPS deviation is
// ~1e-8 relative (see analysis) -> plain masked softmax, no max subtraction.

#define NN 12288
#define DD 128
#define BM 64          // rows per workgroup (16 per wave, 4 waves)
#define BN 32          // key tile
#define KT_LD 136      // Kt row stride (shorts): 128+8 -> 2-way banks (free)
#define VT_LD 40       // Vt row stride (shorts): 32+8  -> 2-way banks (free)
#define PS_LD 40       // P  row stride (shorts)

typedef __attribute__((ext_vector_type(8))) short short8;
typedef __attribute__((ext_vector_type(4))) short short4v;
typedef __attribute__((ext_vector_type(4))) float float4v;

__device__ __forceinline__ short f2bf(float f) {
  // round-to-nearest-even fp32 -> bf16 (inputs finite, no NaN handling)
  unsigned u = __builtin_bit_cast(unsigned, f);
  unsigned r = (u + 0x7FFFu + ((u >> 16) & 1u)) >> 16;
  return (short)r;
}

__global__ __launch_bounds__(256) void attn_kernel(
    const float* __restrict__ Q, const float* __restrict__ K,
    const float* __restrict__ V, const int* __restrict__ seg,
    float* __restrict__ out) {
  __shared__ __align__(16) short Kt[BN * KT_LD];   // 8704 B
  __shared__ __align__(16) short Vt[DD * VT_LD];   // 10240 B (V transposed)
  __shared__ __align__(16) short Ps[4][16 * PS_LD]; // 5120 B (per-wave P tile)

  const int tid  = threadIdx.x;
  const int wave = tid >> 6;
  const int lane = tid & 63;
  const int c    = lane & 15;   // MFMA col / A-row index
  const int quad = lane >> 4;

  const int m0 = blockIdx.x * BM;
  const int i0 = m0 + wave * 16;

  // --- segment range for this block's rows (uniform across threads) ---
  const int segFirst = seg[m0];
  const int segLast  = seg[m0 + BM - 1];
  int lo = 0, hb = NN;
  while (lo < hb) { int mid = (lo + hb) >> 1; if (seg[mid] < segFirst) lo = mid + 1; else hb = mid; }
  int hi = lo, hb2 = NN;
  while (hi < hb2) { int mid = (hi + hb2) >> 1; if (seg[mid] <= segLast) hi = mid + 1; else hb2 = mid; }

  // --- resident Q A-fragments: lane holds Q[i0+c][kc*32 + quad*8 .. +7] ---
  short8 qf[4];
  {
    const float* qrow = Q + (size_t)(i0 + c) * DD + quad * 8;
#pragma unroll
    for (int kc = 0; kc < 4; ++kc) {
      float4v f0 = *(const float4v*)(qrow + kc * 32);
      float4v f1 = *(const float4v*)(qrow + kc * 32 + 4);
      short8 s;
      s[0] = f2bf(f0[0]); s[1] = f2bf(f0[1]); s[2] = f2bf(f0[2]); s[3] = f2bf(f0[3]);
      s[4] = f2bf(f1[0]); s[5] = f2bf(f1[1]); s[6] = f2bf(f1[2]); s[7] = f2bf(f1[3]);
      qf[kc] = s;
    }
  }

  int seg_r[4];
#pragma unroll
  for (int r = 0; r < 4; ++r) seg_r[r] = seg[i0 + quad * 4 + r];

  float4v acc[8];
#pragma unroll
  for (int n = 0; n < 8; ++n) acc[n] = (float4v){0.f, 0.f, 0.f, 0.f};
  float l_part[4] = {0.f, 0.f, 0.f, 0.f};

  const float scale = 0.08838834764831845f; // 1/sqrt(128)

  for (int j0 = lo; j0 < hi; j0 += BN) {
    __syncthreads();  // previous iteration's LDS reads done

    // --- stage K tile -> bf16 LDS [32][128] (padded) ---
    {
      int row = tid >> 3, ch = tid & 7;
      int jj = j0 + row; if (jj > NN - 1) jj = NN - 1;
      const float* kp = K + (size_t)jj * DD + ch * 16;
      short* dst = &Kt[row * KT_LD + ch * 16];
#pragma unroll
      for (int q4 = 0; q4 < 4; ++q4) {
        float4v f = *(const float4v*)(kp + q4 * 4);
        short4v s;
        s[0] = f2bf(f[0]); s[1] = f2bf(f[1]); s[2] = f2bf(f[2]); s[3] = f2bf(f[3]);
        *(short4v*)(dst + q4 * 4) = s;
      }
    }
    // --- stage V tile transposed -> bf16 LDS [128][32] (padded) ---
    {
      int d = tid & 127, jh = tid >> 7;  // jh in {0,1}
      float vv[16];
#pragma unroll
      for (int j = 0; j < 16; ++j) {
        int jj = j0 + jh * 16 + j; if (jj > NN - 1) jj = NN - 1;
        vv[j] = V[(size_t)jj * DD + d];
      }
      short8 a, b;
#pragma unroll
      for (int j = 0; j < 8; ++j) { a[j] = f2bf(vv[j]); b[j] = f2bf(vv[8 + j]); }
      *(short8*)&Vt[d * VT_LD + jh * 16]     = a;
      *(short8*)&Vt[d * VT_LD + jh * 16 + 8] = b;
    }
    __syncthreads();

    // --- S = Q K^T for 16 rows x 32 cols ---
    float4v s0 = (float4v){0.f, 0.f, 0.f, 0.f};
    float4v s1 = (float4v){0.f, 0.f, 0.f, 0.f};
    const short* krow0 = &Kt[c * KT_LD + quad * 8];
    const short* krow1 = &Kt[(16 + c) * KT_LD + quad * 8];
#pragma unroll
    for (int kc = 0; kc < 4; ++kc) {
      short8 b0 = *(const short8*)(krow0 + kc * 32);
      short8 b1 = *(const short8*)(krow1 + kc * 32);
      s0 = __builtin_amdgcn_mfma_f32_16x16x32_bf16(qf[kc], b0, s0, 0, 0, 0);
      s1 = __builtin_amdgcn_mfma_f32_16x16x32_bf16(qf[kc], b1, s1, 0, 0, 0);
    }

    // --- mask + exp, accumulate row-sum partials, P -> LDS (A-layout feed) ---
    int ja = j0 + c, jb = ja + 16;
    int sa = seg[ja < NN ? ja : NN - 1];
    int sb = seg[jb < NN ? jb : NN - 1];
    bool va = ja < hi, vb = jb < hi;
    short* prow = &Ps[wave][0];
#pragma unroll
    for (int r = 0; r < 4; ++r) {
      float pa = (va && sa == seg_r[r]) ? __expf(s0[r] * scale) : 0.f;
      float pb = (vb && sb == seg_r[r]) ? __expf(s1[r] * scale) : 0.f;
      l_part[r] += pa + pb;
      int row = quad * 4 + r;  // C-layout row within 16-row tile
      prow[row * PS_LD + c]      = f2bf(pa);
      prow[row * PS_LD + 16 + c] = f2bf(pb);
    }
    __asm__ volatile("s_waitcnt lgkmcnt(0)" ::: "memory");  // in-wave P write->read

    // --- O += P V : A-frag of P, B-frags from V^T ---
    short8 pf = *(const short8*)&Ps[wave][c * PS_LD + quad * 8];
#pragma unroll
    for (int n = 0; n < 8; ++n) {
      short8 vf = *(const short8*)&Vt[(n * 16 + c) * VT_LD + quad * 8];
      acc[n] = __builtin_amdgcn_mfma_f32_16x16x32_bf16(pf, vf, acc[n], 0, 0, 0);
    }
  }

  // --- row sums (reduce over 16 lanes sharing a quad) + normalize + store ---
  float linv[4];
#pragma unroll
  for (int r = 0; r < 4; ++r) {
    float l = l_part[r];
    l += __shfl_xor(l, 1, 64);
    l += __shfl_xor(l, 2, 64);
    l += __shfl_xor(l, 4, 64);
    l += __shfl_xor(l, 8, 64);
    linv[r] = 1.f / (l + 1e-8f);
  }
#pragma unroll
  for (int n = 0; n < 8; ++n) {
#pragma unroll
    for (int r = 0; r < 4; ++r) {
      out[(size_t)(i0 + quad * 4 + r) * DD + n * 16 + c] = acc[n][r] * linv[r];
    }
  }
}

extern "C" void kernel_launch(void* const* d_in, const int* in_sizes, int n_in,
                              void* d_out, int out_size, void* d_ws, size_t ws_size,
                              hipStream_t stream) {
  const float* Q = (const float*)d_in[0];
  const float* K = (const float*)d_in[1];
  const float* V = (const float*)d_in[2];
  // d_in[3] = num_batch (scalar, unused: mask derived from batch_seg directly)
  const int* seg = (const int*)d_in[4];
  float* out = (float*)d_out;
  attn_kernel<<<NN / BM, 256, 0, stream>>>(Q, K, V, seg, out);
}